// Round 4
// baseline (491.750 us; speedup 1.0000x reference)
//
#include <hip/hip_runtime.h>

#define BATCH 8
#define SEQ   2500
#define DIM   128
#define NC    8921

#define LT    64
#define CT    128
#define NWAVE 4
#define NCH   ((SEQ + LT - 1) / LT)   // 40 (even -> 2x unrolled loop OK)
#define LPAD  (NCH * LT)              // 2560

// P buffer: per-wave 32 rows (c-local, both mt halves) x 64 shorts (l),
// granule-XOR swizzled. 4 KB per wave, 16 KB total.
#define PS_STRIDE 64    // shorts; 128 B rows

typedef __attribute__((ext_vector_type(8))) short        short8;
typedef __attribute__((ext_vector_type(4))) float        float4v;
typedef __attribute__((ext_vector_type(4))) unsigned int uint4v;
typedef __attribute__((ext_vector_type(2))) unsigned int uint2v;

// fp32 -> bf16, round-to-nearest-even (finite inputs only)
__device__ __forceinline__ unsigned int f32_to_bf16_bits(float f) {
    unsigned int u = __builtin_bit_cast(unsigned int, f);
    return (u + 0x7FFFu + ((u >> 16) & 1u)) >> 16;
}
__device__ __forceinline__ unsigned int pack_bf16x2(float a, float b) {
    return f32_to_bf16_bits(a) | (f32_to_bf16_bits(b) << 16);
}
__device__ __forceinline__ short to_bf16(float a) {
    return (short)f32_to_bf16_bits(a);
}

// async global->LDS, 16 B per lane; LDS dest = wave-uniform base + lane*16
__device__ __forceinline__ void async_copy16(const short* g, short* l) {
    __builtin_amdgcn_global_load_lds(
        (__attribute__((address_space(1))) void*)(void*)g,
        (__attribute__((address_space(3))) void*)(void*)l,
        16, 0, 0);
}

// ============================ pre-pass ============================
// x fp32 (8,2500,128) -> XB bf16 [8][2560][128], XT bf16 [8][128][2560]
__global__ __launch_bounds__(256)
void lwa_prepass(const float* __restrict__ x,
                 short* __restrict__ XB, short* __restrict__ XT) {
    const int t  = threadIdx.x;
    const int b  = blockIdx.x / NCH;
    const int lt = blockIdx.x % NCH;
    const int l0 = lt * LT;
    const float* xb = x + (size_t)b * SEQ * DIM;

    {   // XB [l][d]
        const int rowg = t >> 5;
        const int col  = (t & 31) * 4;
#pragma unroll
        for (int i = 0; i < 8; ++i) {
            int row = i * 8 + rowg;
            int l   = l0 + row;
            float4v v = (float4v){0.f, 0.f, 0.f, 0.f};
            if (l < SEQ) v = *(const float4v*)(xb + (size_t)l * DIM + col);
            uint2v pv;
            pv[0] = pack_bf16x2(v[0], v[1]);
            pv[1] = pack_bf16x2(v[2], v[3]);
            *(uint2v*)&XB[((size_t)b * LPAD + l) * DIM + col] = pv;
        }
    }
    {   // XT [d][l] via in-register 8x4 transpose
        const int d4  = (t & 31) * 4;
        const int lg8 = (t >> 5) * 8;
        float4v vv[8];
#pragma unroll
        for (int k = 0; k < 8; ++k) {
            int l = l0 + lg8 + k;
            float4v v = (float4v){0.f, 0.f, 0.f, 0.f};
            if (l < SEQ) v = *(const float4v*)(xb + (size_t)l * DIM + d4);
            vv[k] = v;
        }
#pragma unroll
        for (int c = 0; c < 4; ++c) {
            uint4v fu;
            fu[0] = pack_bf16x2(vv[0][c], vv[1][c]);
            fu[1] = pack_bf16x2(vv[2][c], vv[3][c]);
            fu[2] = pack_bf16x2(vv[4][c], vv[5][c]);
            fu[3] = pack_bf16x2(vv[6][c], vv[7][c]);
            *(uint4v*)&XT[((size_t)b * DIM + d4 + c) * LPAD + l0 + lg8] = fu;
        }
    }
}

// ============================ main kernel ============================
// R9 = R1 structure (BOTH LDS stagings restored; XT-direct-L2 of R8 was 1.8x
// slower: wave-private scattered L2 loads exposed ~16 round trips/chunk) +
// software-pipelined GEMM1 one chunk ahead:
//   iter ch:  prefetch Xs(ch+2)->Xs[ch&1], XT(ch+1)->XTs[~cb]
//             Bf2(ch) ds_reads  |  exp(S_in=S(ch)) -> P -> Af   (serial chain)
//             GEMM1(ch+1) -> S_out                              (independent!)
//             GEMM2(ch) -> Oacc
//             one barrier
// The exp+P+lgkm+Af chain now hides under GEMM1's 32 MFMAs instead of
// serializing between the two GEMMs. S double-buffered in NAMED registers
// (SA/SB, manual 2x unroll -- runtime-indexed S would go to scratch).
// Buffer safety: Xs[ch&1] last read by GEMM1(ch) in iter ch-1 (barrier-
// protected); extra prologue barrier protects Xs[0] from iter-0's prefetch.
// LDS = 32K Xs + 32K XTs + 16K Ps = 80 KB -> 2 blocks/CU (unchanged).
// Unified regs ~ <=230 incl. 64 AGPR Oacc, under the (256,2) cap of 256.
__device__ __forceinline__ void chunk_body(
    int ch, int wave, int r, int q, int psw,
    short (&XsB)[2][LT * DIM], short (&XTsB)[2][DIM * LT], short* Pw,
    const short* const (&gXs)[4], const short* const (&gXT)[4],
    const short8 (&Uf)[2][4], float4v (&Oacc)[2][8], float (&sume)[2],
    const float4v (&S_in)[2][4], float4v (&S_out)[2][4]) {

    const int cb = ch & 1;
    const int l0 = ch * LT;

    // ---- prefetch Xs(ch+2) into Xs[cb]; XT(ch+1) into XTs[cb^1] ----
    if (ch + 2 < NCH) {
#pragma unroll
        for (int j = 0; j < 4; ++j)
            async_copy16(gXs[j] + (size_t)(ch + 2) * (LT * DIM),
                         &XsB[cb][(wave * 4 + j) * 512]);
    }
    if (ch + 1 < NCH) {
#pragma unroll
        for (int j = 0; j < 4; ++j)
            async_copy16(gXT[j] + (size_t)(ch + 1) * LT,
                         &XTsB[cb ^ 1][(wave * 4 + j) * 512]);
    }

    // ---- Bf2(ch): GEMM2 B-fragments from XTs[cb] (16 b128) ----
    short8 Bf2[2][8];
#pragma unroll
    for (int kk = 0; kk < 2; ++kk)
#pragma unroll
        for (int nt = 0; nt < 8; ++nt)
            Bf2[kk][nt] = *(const short8*)&XTsB[cb][(nt * 16 + r) * LT +
                                                    (((kk * 4 + q) ^ (r & 7)) << 3)];

    // ---- exp(S_in) -> packed P for BOTH mt halves (8 b64, swizzled) ----
#pragma unroll
    for (int mt = 0; mt < 2; ++mt) {
#pragma unroll
        for (int nt = 0; nt < 4; ++nt) {
            float ev[4];
#pragma unroll
            for (int reg = 0; reg < 4; ++reg) {
                const int l = l0 + nt * 16 + q * 4 + reg;
                float e = __expf(S_in[mt][nt][reg]);
                e = (l < SEQ) ? e : 0.f;
                sume[mt] += e;
                ev[reg] = e;
            }
            uint2v pv;
            pv[0] = pack_bf16x2(ev[0], ev[1]);
            pv[1] = pack_bf16x2(ev[2], ev[3]);
            const int g = (nt * 4 + q) ^ psw;      // logical granule ^ key
            *(uint2v*)&Pw[(mt * 16 + r) * PS_STRIDE + (g << 2)] = pv;
        }
    }

    // ---- GEMM1(ch+1) from Xs[cb^1] -> S_out (independent of exp chain) ----
    if (ch + 1 < NCH) {
#pragma unroll
        for (int mt = 0; mt < 2; ++mt)
#pragma unroll
            for (int nt = 0; nt < 4; ++nt)
                S_out[mt][nt] = (float4v){0.f, 0.f, 0.f, 0.f};
#pragma unroll
        for (int k = 0; k < 4; ++k) {
            short8 Bf[4];
#pragma unroll
            for (int nt = 0; nt < 4; ++nt)
                Bf[nt] = *(const short8*)&XsB[cb ^ 1][(nt * 16 + r) * DIM +
                                                      (((k * 4 + q) ^ (r & 7)) << 3)];
#pragma unroll
            for (int mt = 0; mt < 2; ++mt)
#pragma unroll
                for (int nt = 0; nt < 4; ++nt)
                    S_out[mt][nt] = __builtin_amdgcn_mfma_f32_16x16x32_bf16(
                        Bf[nt], Uf[mt][k], S_out[mt][nt], 0, 0, 0);
        }
    }

    // ---- Af(ch): read all 4 fragments (one lgkm chain) ----
    short8 Af[2][2];
#pragma unroll
    for (int mt = 0; mt < 2; ++mt)
#pragma unroll
        for (int kk = 0; kk < 2; ++kk) {
            const int g0 = ((kk * 8) + (q << 1)) ^ psw;  // even -> contiguous pair
            Af[mt][kk] = *(const short8*)&Pw[(mt * 16 + r) * PS_STRIDE + (g0 << 2)];
        }

    // ---- GEMM2(ch): Oacc += P . XT  (32 MFMA) ----
#pragma unroll
    for (int kk = 0; kk < 2; ++kk)
#pragma unroll
        for (int nt = 0; nt < 8; ++nt)
#pragma unroll
            for (int mt = 0; mt < 2; ++mt)
                Oacc[mt][nt] = __builtin_amdgcn_mfma_f32_16x16x32_bf16(
                    Af[mt][kk], Bf2[kk][nt], Oacc[mt][nt], 0, 0, 0);

    __syncthreads();   // publishes prefetches; protects buffers for next iter
}

__global__ __launch_bounds__(256, 2)
void lwa_main(const short* __restrict__ XB, const short* __restrict__ XT,
              const float* __restrict__ U, float* __restrict__ out) {
    __shared__ __align__(16) short XsB[2][LT * DIM];            // 2 x 16 KB
    __shared__ __align__(16) short XTsB[2][DIM * LT];           // 2 x 16 KB
    __shared__ __align__(16) short Ps[NWAVE * 32 * PS_STRIDE];  // 16 KB

    const int t    = threadIdx.x;
    const int wave = t >> 6;
    const int lane = t & 63;
    const int r    = lane & 15;
    const int q    = lane >> 4;

    const int b  = blockIdx.x % BATCH;            // batch -> XCD/L2 affinity
    const int cw = (blockIdx.x / BATCH) * CT + wave * 32;

    short* Pw = &Ps[wave * 32 * PS_STRIDE];
    const int psw = (r & 7) << 1;                 // granule XOR key (even)

    // ---- staging source pointers (per lane, chunk 0) ----
    const short* gXs[4];
    const short* gXT[4];
#pragma unroll
    for (int j = 0; j < 4; ++j) {
        int p    = (wave * 4 + j) * 64 + lane;   // granule index in chunk
        int row  = p >> 4;                        // Xs: 16 granules/row
        int gcol = (p & 15) ^ (row & 7);
        gXs[j] = XB + (size_t)b * LPAD * DIM + row * DIM + gcol * 8;
        int rowd  = p >> 3;                       // XT: 8 granules/row
        int gcol2 = (p & 7) ^ (rowd & 7);
        gXT[j] = XT + ((size_t)b * DIM + rowd) * LPAD + gcol2 * 8;
    }

    // ---- U fragments in registers: Uf[mt][k] holds U[c=r][d=k*32+q*8+j] ----
    short8 Uf[2][4];
#pragma unroll
    for (int mt = 0; mt < 2; ++mt) {
        int c = cw + mt * 16 + r;
        if (c >= NC) c = NC - 1;                  // clamp; stores masked later
        const float* up = U + (size_t)c * DIM + q * 8;
#pragma unroll
        for (int k = 0; k < 4; ++k) {
            float4v a  = *(const float4v*)(up + k * 32);
            float4v b2 = *(const float4v*)(up + k * 32 + 4);
            uint4v fu;
            fu[0] = pack_bf16x2(a[0], a[1]);
            fu[1] = pack_bf16x2(a[2], a[3]);
            fu[2] = pack_bf16x2(b2[0], b2[1]);
            fu[3] = pack_bf16x2(b2[2], b2[3]);
            Uf[mt][k] = __builtin_bit_cast(short8, fu);
        }
    }

    float4v Oacc[2][8];
#pragma unroll
    for (int mt = 0; mt < 2; ++mt)
#pragma unroll
        for (int nt = 0; nt < 8; ++nt)
            Oacc[mt][nt] = (float4v){0.f, 0.f, 0.f, 0.f};

    float sume[2] = {0.f, 0.f};

    // ---- prologue: stage Xs(0)->Xs[0], XT(0)->XTs[0], Xs(1)->Xs[1] ----
#pragma unroll
    for (int j = 0; j < 4; ++j) {
        async_copy16(gXs[j], &XsB[0][(wave * 4 + j) * 512]);
        async_copy16(gXT[j], &XTsB[0][(wave * 4 + j) * 512]);
        async_copy16(gXs[j] + (size_t)(LT * DIM), &XsB[1][(wave * 4 + j) * 512]);
    }
    __syncthreads();   // chunk 0 + Xs(1) staged

    // ---- prologue GEMM1(0) -> SA ----
    float4v SA[2][4], SB[2][4];
#pragma unroll
    for (int mt = 0; mt < 2; ++mt)
#pragma unroll
        for (int nt = 0; nt < 4; ++nt)
            SA[mt][nt] = (float4v){0.f, 0.f, 0.f, 0.f};
#pragma unroll
    for (int k = 0; k < 4; ++k) {
        short8 Bf[4];
#pragma unroll
        for (int nt = 0; nt < 4; ++nt)
            Bf[nt] = *(const short8*)&XsB[0][(nt * 16 + r) * DIM +
                                            (((k * 4 + q) ^ (r & 7)) << 3)];
#pragma unroll
        for (int mt = 0; mt < 2; ++mt)
#pragma unroll
            for (int nt = 0; nt < 4; ++nt)
                SA[mt][nt] = __builtin_amdgcn_mfma_f32_16x16x32_bf16(
                    Bf[nt], Uf[mt][k], SA[mt][nt], 0, 0, 0);
    }
    __syncthreads();   // all waves done reading Xs[0] before iter-0 prefetch

    // ---- main loop: 2x unrolled so S buffers are statically named ----
    for (int ch = 0; ch < NCH; ch += 2) {
        chunk_body(ch,     wave, r, q, psw, XsB, XTsB, Pw, gXs, gXT,
                   Uf, Oacc, sume, SA, SB);
        chunk_body(ch + 1, wave, r, q, psw, XsB, XTsB, Pw, gXs, gXT,
                   Uf, Oacc, sume, SB, SA);
    }

    // ---- reduce sumexp across the 4 q-groups (c = mt*16 + r fixed/lane) ----
    float inv[2];
#pragma unroll
    for (int mt = 0; mt < 2; ++mt) {
        float s = sume[mt];
        s += __shfl_xor(s, 16, 64);
        s += __shfl_xor(s, 32, 64);
        inv[mt] = 1.0f / s;
    }

    // ---- normalize + store: c = cw + mt*16 + q*4 + reg, d = nt*16 + r ----
#pragma unroll
    for (int mt = 0; mt < 2; ++mt) {
#pragma unroll
        for (int reg = 0; reg < 4; ++reg) {
            const int c = cw + mt * 16 + q * 4 + reg;
            // shfl BEFORE the divergent branch: all lanes must participate
            const float iv = __shfl(inv[mt], q * 4 + reg, 64);
            if (c < NC) {
                float* op = out + ((size_t)b * NC + c) * DIM + r;
#pragma unroll
                for (int nt = 0; nt < 8; ++nt)
                    op[nt * 16] = Oacc[mt][nt][reg] * iv;
            }
        }
    }
}

// ============================ fallback (R2, verified) ============================
#define XS_STRIDE 136
#define XT_STRIDE 72

__global__ __launch_bounds__(256, 2)
void lwa_fallback(const float* __restrict__ x,
                  const float* __restrict__ U,
                  float* __restrict__ out) {
    __shared__ __align__(16) short Xs[LT * XS_STRIDE];
    __shared__ __align__(16) short XTs[DIM * XT_STRIDE];
    __shared__ __align__(16) short Psf[4 * 32 * XT_STRIDE];

    const int t    = threadIdx.x;
    const int wave = t >> 6;
    const int lane = t & 63;
    const int r    = lane & 15;
    const int q    = lane >> 4;

    const int b  = blockIdx.x % BATCH;
    const int cw = (blockIdx.x / BATCH) * 128 + wave * 32;

    const float* xb = x + (size_t)b * SEQ * DIM;
    short* Pw = &Psf[wave * 32 * XT_STRIDE];

    short8 Uf[2][4];
#pragma unroll
    for (int mt = 0; mt < 2; ++mt) {
        int c = cw + mt * 16 + r;
        if (c >= NC) c = NC - 1;
        const float* up = U + (size_t)c * DIM + q * 8;
#pragma unroll
        for (int k = 0; k < 4; ++k) {
            float4v a  = *(const float4v*)(up + k * 32);
            float4v b2 = *(const float4v*)(up + k * 32 + 4);
            uint4v fu;
            fu[0] = pack_bf16x2(a[0], a[1]);
            fu[1] = pack_bf16x2(a[2], a[3]);
            fu[2] = pack_bf16x2(b2[0], b2[1]);
            fu[3] = pack_bf16x2(b2[2], b2[3]);
            Uf[mt][k] = __builtin_bit_cast(short8, fu);
        }
    }

    float4v Oacc[2][8];
#pragma unroll
    for (int mt = 0; mt < 2; ++mt)
#pragma unroll
        for (int nt = 0; nt < 8; ++nt)
            Oacc[mt][nt] = (float4v){0.f, 0.f, 0.f, 0.f};

    float sume[2][4] = {{0.f, 0.f, 0.f, 0.f}, {0.f, 0.f, 0.f, 0.f}};

    for (int ch = 0; ch < NCH; ++ch) {
        const int l0 = ch * LT;
        __syncthreads();
        {
            const int rowg = t >> 5;
            const int col  = (t & 31) * 4;
#pragma unroll
            for (int i = 0; i < 8; ++i) {
                int row = i * 8 + rowg;
                int l   = l0 + row;
                float4v v = (float4v){0.f, 0.f, 0.f, 0.f};
                if (l < SEQ) v = *(const float4v*)(xb + (size_t)l * DIM + col);
                uint2v pv;
                pv[0] = pack_bf16x2(v[0], v[1]);
                pv[1] = pack_bf16x2(v[2], v[3]);
                *(uint2v*)&Xs[row * XS_STRIDE + col] = pv;
            }
        }
        {
            const int d4  = (t & 31) * 4;
            const int lg8 = (t >> 5) * 8;
            float4v vv[8];
#pragma unroll
            for (int k = 0; k < 8; ++k) {
                int l = l0 + lg8 + k;
                float4v v = (float4v){0.f, 0.f, 0.f, 0.f};
                if (l < SEQ) v = *(const float4v*)(xb + (size_t)l * DIM + d4);
                vv[k] = v;
            }
#pragma unroll
            for (int c = 0; c < 4; ++c) {
                uint4v fu;
                fu[0] = pack_bf16x2(vv[0][c], vv[1][c]);
                fu[1] = pack_bf16x2(vv[2][c], vv[3][c]);
                fu[2] = pack_bf16x2(vv[4][c], vv[5][c]);
                fu[3] = pack_bf16x2(vv[6][c], vv[7][c]);
                *(uint4v*)&XTs[(d4 + c) * XT_STRIDE + lg8] = fu;
            }
        }
        __syncthreads();

        float4v S[2][4];
#pragma unroll
        for (int mt = 0; mt < 2; ++mt)
#pragma unroll
            for (int nt = 0; nt < 4; ++nt)
                S[mt][nt] = (float4v){0.f, 0.f, 0.f, 0.f};
#pragma unroll
        for (int k = 0; k < 4; ++k) {
            short8 Bf[4];
#pragma unroll
            for (int nt = 0; nt < 4; ++nt)
                Bf[nt] = *(const short8*)&Xs[(nt * 16 + r) * XS_STRIDE + k * 32 + q * 8];
#pragma unroll
            for (int mt = 0; mt < 2; ++mt)
#pragma unroll
                for (int nt = 0; nt < 4; ++nt)
                    S[mt][nt] = __builtin_amdgcn_mfma_f32_16x16x32_bf16(
                        Uf[mt][k], Bf[nt], S[mt][nt], 0, 0, 0);
        }

#pragma unroll
        for (int mt = 0; mt < 2; ++mt)
#pragma unroll
            for (int nt = 0; nt < 4; ++nt) {
                const int  l     = l0 + nt * 16 + r;
                const bool valid = (l < SEQ);
#pragma unroll
                for (int reg = 0; reg < 4; ++reg) {
                    float e = __expf(S[mt][nt][reg]);
                    e = valid ? e : 0.f;
                    sume[mt][reg] += e;
                    Pw[(mt * 16 + q * 4 + reg) * XT_STRIDE + nt * 16 + r] = to_bf16(e);
                }
            }

#pragma unroll
        for (int k = 0; k < 2; ++k) {
            short8 Af[2];
#pragma unroll
            for (int mt = 0; mt < 2; ++mt)
                Af[mt] = *(const short8*)&Pw[(mt * 16 + r) * XT_STRIDE + k * 32 + q * 8];
#pragma unroll
            for (int nt = 0; nt < 8; ++nt) {
                short8 Bf = *(const short8*)&XTs[(nt * 16 + r) * XT_STRIDE + k * 32 + q * 8];
#pragma unroll
                for (int mt = 0; mt < 2; ++mt)
                    Oacc[mt][nt] = __builtin_amdgcn_mfma_f32_16x16x32_bf16(
                        Af[mt], Bf, Oacc[mt][nt], 0, 0, 0);
            }
        }
    }

#pragma unroll
    for (int mt = 0; mt < 2; ++mt)
#pragma unroll
        for (int reg = 0; reg < 4; ++reg) {
            float s = sume[mt][reg];
            s += __shfl_xor(s, 1, 64);
            s += __shfl_xor(s, 2, 64);
            s += __shfl_xor(s, 4, 64);
            s += __shfl_xor(s, 8, 64);
            sume[mt][reg] = 1.0f / s;
        }

#pragma unroll
    for (int mt = 0; mt < 2; ++mt) {
#pragma unroll
        for (int reg = 0; reg < 4; ++reg) {
            const int c = cw + mt * 16 + q * 4 + reg;
            if (c < NC) {
                const float inv = sume[mt][reg];
                float* op = out + ((size_t)b * NC + c) * DIM + r;
#pragma unroll
                for (int nt = 0; nt < 8; ++nt)
                    op[nt * 16] = Oacc[mt][nt][reg] * inv;
            }
        }
    }
}

extern "C" void kernel_launch(void* const* d_in, const int* in_sizes, int n_in,
                              void* d_out, int out_size, void* d_ws, size_t ws_size,
                              hipStream_t stream) {
    const float* x = (const float*)d_in[0];   // (8, 2500, 128) fp32
    const float* U = (const float*)d_in[1];   // (8921, 128) fp32
    float* out = (float*)d_out;               // (8, 8921, 128) fp32
    const int nblocks = BATCH * ((NC + CT - 1) / CT);   // 560

    const size_t need = 2 * (size_t)BATCH * LPAD * DIM * sizeof(short);  // 10.5 MB
    if (ws_size >= need) {
        short* XB = (short*)d_ws;
        short* XT = XB + (size_t)BATCH * LPAD * DIM;
        lwa_prepass<<<dim3(BATCH * NCH), dim3(256), 0, stream>>>(x, XB, XT);
        lwa_main<<<dim3(nblocks), dim3(256), 0, stream>>>(XB, XT, U, out);
    } else {
        lwa_fallback<<<dim3(nblocks), dim3(256), 0, stream>>>(x, U, out);
    }
}

// Round 5
// 222.684 us; speedup vs baseline: 2.2083x; 2.2083x over previous
//
#include <hip/hip_runtime.h>

#define BATCH 8
#define SEQ   2500
#define DIM   128
#define NC    8921

#define LT    64
#define CT    128
#define NWAVE 4
#define NCH   ((SEQ + LT - 1) / LT)   // 40
#define LPAD  (NCH * LT)              // 2560

// P buffer: per-wave 32 rows (c-local, both mt halves) x 64 shorts (l),
// granule-XOR swizzled. 4 KB per wave, 16 KB total.
#define PS_STRIDE 64    // shorts; 128 B rows

typedef __attribute__((ext_vector_type(8))) short        short8;
typedef __attribute__((ext_vector_type(4))) float        float4v;
typedef __attribute__((ext_vector_type(4))) unsigned int uint4v;
typedef __attribute__((ext_vector_type(2))) unsigned int uint2v;

// fp32 -> bf16, round-to-nearest-even (finite inputs only)
__device__ __forceinline__ unsigned int f32_to_bf16_bits(float f) {
    unsigned int u = __builtin_bit_cast(unsigned int, f);
    return (u + 0x7FFFu + ((u >> 16) & 1u)) >> 16;
}
__device__ __forceinline__ unsigned int pack_bf16x2(float a, float b) {
    return f32_to_bf16_bits(a) | (f32_to_bf16_bits(b) << 16);
}
__device__ __forceinline__ short to_bf16(float a) {
    return (short)f32_to_bf16_bits(a);
}

// async global->LDS, 16 B per lane; LDS dest = wave-uniform base + lane*16
__device__ __forceinline__ void async_copy16(const short* g, short* l) {
    __builtin_amdgcn_global_load_lds(
        (__attribute__((address_space(1))) void*)(void*)g,
        (__attribute__((address_space(3))) void*)(void*)l,
        16, 0, 0);
}

// ============================ pre-pass ============================
// x fp32 (8,2500,128) -> XB bf16 [8][2560][128], XT bf16 [8][128][2560]
__global__ __launch_bounds__(256)
void lwa_prepass(const float* __restrict__ x,
                 short* __restrict__ XB, short* __restrict__ XT) {
    const int t  = threadIdx.x;
    const int b  = blockIdx.x / NCH;
    const int lt = blockIdx.x % NCH;
    const int l0 = lt * LT;
    const float* xb = x + (size_t)b * SEQ * DIM;

    {   // XB [l][d]
        const int rowg = t >> 5;
        const int col  = (t & 31) * 4;
#pragma unroll
        for (int i = 0; i < 8; ++i) {
            int row = i * 8 + rowg;
            int l   = l0 + row;
            float4v v = (float4v){0.f, 0.f, 0.f, 0.f};
            if (l < SEQ) v = *(const float4v*)(xb + (size_t)l * DIM + col);
            uint2v pv;
            pv[0] = pack_bf16x2(v[0], v[1]);
            pv[1] = pack_bf16x2(v[2], v[3]);
            *(uint2v*)&XB[((size_t)b * LPAD + l) * DIM + col] = pv;
        }
    }
    {   // XT [d][l] via in-register 8x4 transpose
        const int d4  = (t & 31) * 4;
        const int lg8 = (t >> 5) * 8;
        float4v vv[8];
#pragma unroll
        for (int k = 0; k < 8; ++k) {
            int l = l0 + lg8 + k;
            float4v v = (float4v){0.f, 0.f, 0.f, 0.f};
            if (l < SEQ) v = *(const float4v*)(xb + (size_t)l * DIM + d4);
            vv[k] = v;
        }
#pragma unroll
        for (int c = 0; c < 4; ++c) {
            uint4v fu;
            fu[0] = pack_bf16x2(vv[0][c], vv[1][c]);
            fu[1] = pack_bf16x2(vv[2][c], vv[3][c]);
            fu[2] = pack_bf16x2(vv[4][c], vv[5][c]);
            fu[3] = pack_bf16x2(vv[6][c], vv[7][c]);
            *(uint4v*)&XT[((size_t)b * DIM + d4 + c) * LPAD + l0 + lg8] = fu;
        }
    }
}

// ============================ main kernel ============================
// R10: occupancy 2 -> 3 blocks/CU. Post-mortems R7/R9: dbuf + hoisted frags
// spill (unified VGPR+AGPR file); the proven low-pressure body is R8's
// single-phase-P structure (measured 104 VGPR + 64 AGPR = 168 unified).
// 168 == the 3-waves/SIMD budget (512/3). So:
//   - BOTH stagings single-buffered: LDS = 16K Xs + 16K XTs + 16K Ps = 48K
//     (<= 53.3K -> 3 blocks/CU by LDS)
//   - __launch_bounds__(256, 3) -> allocator targets <=168 unified
//   - per chunk: stage -> barrier (drains vmcnt) -> GEMM1 -> exp/P -> Af ->
//     GEMM2 (kk-split Bf2: 32 VGPR live, not 64) -> barrier
//   - 560-block grid now runs in ONE round (<= 768 slots), was 2 rounds.
// The exposed staging wait per chunk is hidden by cross-block TLP (3
// blocks/CU), which R1's idle pipes (<25% everything) show is available.
// Abort-signals if this theory is wrong: VGPR>110 / WRITE_SIZE >> 36MB
// (spill), or occupancy up but dur flat (serial chain is the floor).
__global__ __launch_bounds__(256, 3)
void lwa_main(const short* __restrict__ XB, const short* __restrict__ XT,
              const float* __restrict__ U, float* __restrict__ out) {
    __shared__ __align__(16) short Xs[LT * DIM];                // 16 KB
    __shared__ __align__(16) short XTs[DIM * LT];               // 16 KB
    __shared__ __align__(16) short Ps[NWAVE * 32 * PS_STRIDE];  // 16 KB

    const int t    = threadIdx.x;
    const int wave = t >> 6;
    const int lane = t & 63;
    const int r    = lane & 15;
    const int q    = lane >> 4;

    const int b  = blockIdx.x % BATCH;            // batch -> XCD/L2 affinity
    const int cw = (blockIdx.x / BATCH) * CT + wave * 32;

    short* Pw = &Ps[wave * 32 * PS_STRIDE];
    const int psw = (r & 7) << 1;                 // granule XOR key (even)

    // ---- staging source pointers (per lane, advanced in-place per chunk) ----
    const short* gXs[4];
    const short* gXT[4];
#pragma unroll
    for (int j = 0; j < 4; ++j) {
        int p    = (wave * 4 + j) * 64 + lane;   // granule index in chunk
        int row  = p >> 4;                        // Xs: 16 granules/row
        int gcol = (p & 15) ^ (row & 7);
        gXs[j] = XB + (size_t)b * LPAD * DIM + row * DIM + gcol * 8;
        int rowd  = p >> 3;                       // XT: 8 granules/row
        int gcol2 = (p & 7) ^ (rowd & 7);
        gXT[j] = XT + ((size_t)b * DIM + rowd) * LPAD + gcol2 * 8;
    }

    // ---- U fragments in registers: Uf[mt][k] holds U[c=r][d=k*32+q*8+j] ----
    short8 Uf[2][4];
#pragma unroll
    for (int mt = 0; mt < 2; ++mt) {
        int c = cw + mt * 16 + r;
        if (c >= NC) c = NC - 1;                  // clamp; stores masked later
        const float* up = U + (size_t)c * DIM + q * 8;
#pragma unroll
        for (int k = 0; k < 4; ++k) {
            float4v a  = *(const float4v*)(up + k * 32);
            float4v b2 = *(const float4v*)(up + k * 32 + 4);
            uint4v fu;
            fu[0] = pack_bf16x2(a[0], a[1]);
            fu[1] = pack_bf16x2(a[2], a[3]);
            fu[2] = pack_bf16x2(b2[0], b2[1]);
            fu[3] = pack_bf16x2(b2[2], b2[3]);
            Uf[mt][k] = __builtin_bit_cast(short8, fu);
        }
    }

    float4v Oacc[2][8];
#pragma unroll
    for (int mt = 0; mt < 2; ++mt)
#pragma unroll
        for (int nt = 0; nt < 8; ++nt)
            Oacc[mt][nt] = (float4v){0.f, 0.f, 0.f, 0.f};

    float sume[2] = {0.f, 0.f};

    for (int ch = 0; ch < NCH; ++ch) {
        const int l0 = ch * LT;

        // ---- stage Xs(ch) + XTs(ch); prev-chunk reads barrier-protected ----
#pragma unroll
        for (int j = 0; j < 4; ++j) {
            async_copy16(gXs[j], &Xs[(wave * 4 + j) * 512]);
            async_copy16(gXT[j], &XTs[(wave * 4 + j) * 512]);
            gXs[j] += LT * DIM;
            gXT[j] += LT;
        }
        __syncthreads();   // drains vmcnt -> chunk ch staged & visible

        // ---- GEMM1 (swapped): S^T layout, lane (r,q) reg holds
        //      (c = mt*16 + r, l = nt*16 + q*4 + reg) ----
        float4v S[2][4];
#pragma unroll
        for (int mt = 0; mt < 2; ++mt)
#pragma unroll
            for (int nt = 0; nt < 4; ++nt)
                S[mt][nt] = (float4v){0.f, 0.f, 0.f, 0.f};
#pragma unroll
        for (int k = 0; k < 4; ++k) {
            short8 Bf[4];
#pragma unroll
            for (int nt = 0; nt < 4; ++nt)
                Bf[nt] = *(const short8*)&Xs[(nt * 16 + r) * DIM +
                                             (((k * 4 + q) ^ (r & 7)) << 3)];
#pragma unroll
            for (int mt = 0; mt < 2; ++mt)
#pragma unroll
                for (int nt = 0; nt < 4; ++nt)
                    S[mt][nt] = __builtin_amdgcn_mfma_f32_16x16x32_bf16(
                        Bf[nt], Uf[mt][k], S[mt][nt], 0, 0, 0);
        }

        // ---- exp -> packed P for BOTH mt halves (8 b64 writes, swizzled) ----
#pragma unroll
        for (int mt = 0; mt < 2; ++mt) {
#pragma unroll
            for (int nt = 0; nt < 4; ++nt) {
                float ev[4];
#pragma unroll
                for (int reg = 0; reg < 4; ++reg) {
                    const int l = l0 + nt * 16 + q * 4 + reg;
                    float e = __expf(S[mt][nt][reg]);
                    e = (l < SEQ) ? e : 0.f;
                    sume[mt] += e;
                    ev[reg] = e;
                }
                uint2v pv;
                pv[0] = pack_bf16x2(ev[0], ev[1]);
                pv[1] = pack_bf16x2(ev[2], ev[3]);
                const int g = (nt * 4 + q) ^ psw;      // logical granule ^ key
                *(uint2v*)&Pw[(mt * 16 + r) * PS_STRIDE + (g << 2)] = pv;
            }
        }

        // ---- Af: all 4 fragments, one lgkm chain (wave-private Ps; DS ops
        //      within a wave execute in order -> no barrier needed) ----
        short8 Af[2][2];
#pragma unroll
        for (int mt = 0; mt < 2; ++mt)
#pragma unroll
            for (int kk = 0; kk < 2; ++kk) {
                const int g0 = ((kk * 8) + (q << 1)) ^ psw;  // even -> contiguous
                Af[mt][kk] = *(const short8*)&Pw[(mt * 16 + r) * PS_STRIDE +
                                                 (g0 << 2)];
            }

        // ---- GEMM2, kk-split so only 8 Bf2 fragments (32 VGPR) live ----
#pragma unroll
        for (int kk = 0; kk < 2; ++kk) {
            short8 B8[8];
#pragma unroll
            for (int nt = 0; nt < 8; ++nt)
                B8[nt] = *(const short8*)&XTs[(nt * 16 + r) * LT +
                                              (((kk * 4 + q) ^ (r & 7)) << 3)];
#pragma unroll
            for (int nt = 0; nt < 8; ++nt)
#pragma unroll
                for (int mt = 0; mt < 2; ++mt)
                    Oacc[mt][nt] = __builtin_amdgcn_mfma_f32_16x16x32_bf16(
                        Af[mt][kk], B8[nt], Oacc[mt][nt], 0, 0, 0);
        }

        __syncthreads();   // all LDS reads of chunk ch done before restaging
    }

    // ---- reduce sumexp across the 4 q-groups (c = mt*16 + r fixed/lane) ----
    float inv[2];
#pragma unroll
    for (int mt = 0; mt < 2; ++mt) {
        float s = sume[mt];
        s += __shfl_xor(s, 16, 64);
        s += __shfl_xor(s, 32, 64);
        inv[mt] = 1.0f / s;
    }

    // ---- normalize + store: c = cw + mt*16 + q*4 + reg, d = nt*16 + r ----
#pragma unroll
    for (int mt = 0; mt < 2; ++mt) {
#pragma unroll
        for (int reg = 0; reg < 4; ++reg) {
            const int c = cw + mt * 16 + q * 4 + reg;
            // shfl BEFORE the divergent branch: all lanes must participate
            const float iv = __shfl(inv[mt], q * 4 + reg, 64);
            if (c < NC) {
                float* op = out + ((size_t)b * NC + c) * DIM + r;
#pragma unroll
                for (int nt = 0; nt < 8; ++nt)
                    op[nt * 16] = Oacc[mt][nt][reg] * iv;
            }
        }
    }
}

// ============================ fallback (R2, verified) ============================
#define XS_STRIDE 136
#define XT_STRIDE 72

__global__ __launch_bounds__(256, 2)
void lwa_fallback(const float* __restrict__ x,
                  const float* __restrict__ U,
                  float* __restrict__ out) {
    __shared__ __align__(16) short Xs[LT * XS_STRIDE];
    __shared__ __align__(16) short XTs[DIM * XT_STRIDE];
    __shared__ __align__(16) short Psf[4 * 32 * XT_STRIDE];

    const int t    = threadIdx.x;
    const int wave = t >> 6;
    const int lane = t & 63;
    const int r    = lane & 15;
    const int q    = lane >> 4;

    const int b  = blockIdx.x % BATCH;
    const int cw = (blockIdx.x / BATCH) * 128 + wave * 32;

    const float* xb = x + (size_t)b * SEQ * DIM;
    short* Pw = &Psf[wave * 32 * XT_STRIDE];

    short8 Uf[2][4];
#pragma unroll
    for (int mt = 0; mt < 2; ++mt) {
        int c = cw + mt * 16 + r;
        if (c >= NC) c = NC - 1;
        const float* up = U + (size_t)c * DIM + q * 8;
#pragma unroll
        for (int k = 0; k < 4; ++k) {
            float4v a  = *(const float4v*)(up + k * 32);
            float4v b2 = *(const float4v*)(up + k * 32 + 4);
            uint4v fu;
            fu[0] = pack_bf16x2(a[0], a[1]);
            fu[1] = pack_bf16x2(a[2], a[3]);
            fu[2] = pack_bf16x2(b2[0], b2[1]);
            fu[3] = pack_bf16x2(b2[2], b2[3]);
            Uf[mt][k] = __builtin_bit_cast(short8, fu);
        }
    }

    float4v Oacc[2][8];
#pragma unroll
    for (int mt = 0; mt < 2; ++mt)
#pragma unroll
        for (int nt = 0; nt < 8; ++nt)
            Oacc[mt][nt] = (float4v){0.f, 0.f, 0.f, 0.f};

    float sume[2][4] = {{0.f, 0.f, 0.f, 0.f}, {0.f, 0.f, 0.f, 0.f}};

    for (int ch = 0; ch < NCH; ++ch) {
        const int l0 = ch * LT;
        __syncthreads();
        {
            const int rowg = t >> 5;
            const int col  = (t & 31) * 4;
#pragma unroll
            for (int i = 0; i < 8; ++i) {
                int row = i * 8 + rowg;
                int l   = l0 + row;
                float4v v = (float4v){0.f, 0.f, 0.f, 0.f};
                if (l < SEQ) v = *(const float4v*)(xb + (size_t)l * DIM + col);
                uint2v pv;
                pv[0] = pack_bf16x2(v[0], v[1]);
                pv[1] = pack_bf16x2(v[2], v[3]);
                *(uint2v*)&Xs[row * XS_STRIDE + col] = pv;
            }
        }
        {
            const int d4  = (t & 31) * 4;
            const int lg8 = (t >> 5) * 8;
            float4v vv[8];
#pragma unroll
            for (int k = 0; k < 8; ++k) {
                int l = l0 + lg8 + k;
                float4v v = (float4v){0.f, 0.f, 0.f, 0.f};
                if (l < SEQ) v = *(const float4v*)(xb + (size_t)l * DIM + d4);
                vv[k] = v;
            }
#pragma unroll
            for (int c = 0; c < 4; ++c) {
                uint4v fu;
                fu[0] = pack_bf16x2(vv[0][c], vv[1][c]);
                fu[1] = pack_bf16x2(vv[2][c], vv[3][c]);
                fu[2] = pack_bf16x2(vv[4][c], vv[5][c]);
                fu[3] = pack_bf16x2(vv[6][c], vv[7][c]);
                *(uint4v*)&XTs[(d4 + c) * XT_STRIDE + lg8] = fu;
            }
        }
        __syncthreads();

        float4v S[2][4];
#pragma unroll
        for (int mt = 0; mt < 2; ++mt)
#pragma unroll
            for (int nt = 0; nt < 4; ++nt)
                S[mt][nt] = (float4v){0.f, 0.f, 0.f, 0.f};
#pragma unroll
        for (int k = 0; k < 4; ++k) {
            short8 Bf[4];
#pragma unroll
            for (int nt = 0; nt < 4; ++nt)
                Bf[nt] = *(const short8*)&Xs[(nt * 16 + r) * XS_STRIDE + k * 32 + q * 8];
#pragma unroll
            for (int mt = 0; mt < 2; ++mt)
#pragma unroll
                for (int nt = 0; nt < 4; ++nt)
                    S[mt][nt] = __builtin_amdgcn_mfma_f32_16x16x32_bf16(
                        Uf[mt][k], Bf[nt], S[mt][nt], 0, 0, 0);
        }

#pragma unroll
        for (int mt = 0; mt < 2; ++mt)
#pragma unroll
            for (int nt = 0; nt < 4; ++nt) {
                const int  l     = l0 + nt * 16 + r;
                const bool valid = (l < SEQ);
#pragma unroll
                for (int reg = 0; reg < 4; ++reg) {
                    float e = __expf(S[mt][nt][reg]);
                    e = valid ? e : 0.f;
                    sume[mt][reg] += e;
                    Pw[(mt * 16 + q * 4 + reg) * XT_STRIDE + nt * 16 + r] = to_bf16(e);
                }
            }

#pragma unroll
        for (int k = 0; k < 2; ++k) {
            short8 Af[2];
#pragma unroll
            for (int mt = 0; mt < 2; ++mt)
                Af[mt] = *(const short8*)&Pw[(mt * 16 + r) * XT_STRIDE + k * 32 + q * 8];
#pragma unroll
            for (int nt = 0; nt < 8; ++nt) {
                short8 Bf = *(const short8*)&XTs[(nt * 16 + r) * XT_STRIDE + k * 32 + q * 8];
#pragma unroll
                for (int mt = 0; mt < 2; ++mt)
                    Oacc[mt][nt] = __builtin_amdgcn_mfma_f32_16x16x32_bf16(
                        Af[mt], Bf, Oacc[mt][nt], 0, 0, 0);
            }
        }
    }

#pragma unroll
    for (int mt = 0; mt < 2; ++mt)
#pragma unroll
        for (int reg = 0; reg < 4; ++reg) {
            float s = sume[mt][reg];
            s += __shfl_xor(s, 1, 64);
            s += __shfl_xor(s, 2, 64);
            s += __shfl_xor(s, 4, 64);
            s += __shfl_xor(s, 8, 64);
            sume[mt][reg] = 1.0f / s;
        }

#pragma unroll
    for (int mt = 0; mt < 2; ++mt) {
#pragma unroll
        for (int reg = 0; reg < 4; ++reg) {
            const int c = cw + mt * 16 + q * 4 + reg;
            if (c < NC) {
                const float inv = sume[mt][reg];
                float* op = out + ((size_t)b * NC + c) * DIM + r;
#pragma unroll
                for (int nt = 0; nt < 8; ++nt)
                    op[nt * 16] = Oacc[mt][nt][reg] * inv;
            }
        }
    }
}

extern "C" void kernel_launch(void* const* d_in, const int* in_sizes, int n_in,
                              void* d_out, int out_size, void* d_ws, size_t ws_size,
                              hipStream_t stream) {
    const float* x = (const float*)d_in[0];   // (8, 2500, 128) fp32
    const float* U = (const float*)d_in[1];   // (8921, 128) fp32
    float* out = (float*)d_out;               // (8, 8921, 128) fp32
    const int nblocks = BATCH * ((NC + CT - 1) / CT);   // 560

    const size_t need = 2 * (size_t)BATCH * LPAD * DIM * sizeof(short);  // 10.5 MB
    if (ws_size >= need) {
        short* XB = (short*)d_ws;
        short* XT = XB + (size_t)BATCH * LPAD * DIM;
        lwa_prepass<<<dim3(BATCH * NCH), dim3(256), 0, stream>>>(x, XB, XT);
        lwa_main<<<dim3(nblocks), dim3(256), 0, stream>>>(XB, XT, U, out);
    } else {
        lwa_fallback<<<dim3(nblocks), dim3(256), 0, stream>>>(x, U, out);
    }
}